// Round 1
// baseline (579.812 us; speedup 1.0000x reference)
//
#include <hip/hip_runtime.h>
#include <math.h>

#define Bn 8
#define Nn 1024
#define Cn 1024
#define Hn 16
#define Dn 64
#define HIDn 4096
#define SCALEf 0.125f

typedef __bf16 bf16x8 __attribute__((ext_vector_type(8)));
typedef float f32x4 __attribute__((ext_vector_type(4)));

__device__ inline unsigned short f2bf(float f) {
    union { float f; unsigned int u; } v; v.f = f;
    unsigned int r = v.u + 0x7fffu + ((v.u >> 16) & 1u);
    return (unsigned short)(r >> 16);
}

__device__ inline void gload_lds16(const void* g, void* l) {
    auto gp = reinterpret_cast<const unsigned int __attribute__((address_space(1)))*>(
        reinterpret_cast<uintptr_t>(g));
    auto lp = reinterpret_cast<unsigned int __attribute__((address_space(3)))*>(
        reinterpret_cast<uintptr_t>(l));
    __builtin_amdgcn_global_load_lds(gp, lp, 16, 0, 0);
}

// ---------------- f32 -> bf16 conversion ----------------
__global__ __launch_bounds__(256) void cvt_bf16(const float* __restrict__ in,
                                                unsigned short* __restrict__ out, int n4) {
    int i = blockIdx.x * 256 + threadIdx.x;
    if (i < n4) {
        float4 v = ((const float4*)in)[i];
        ushort4 o;
        o.x = f2bf(v.x); o.y = f2bf(v.y); o.z = f2bf(v.z); o.w = f2bf(v.w);
        ((ushort4*)out)[i] = o;
    }
}

// ---------------- LayerNorm (C=1024), fp32 in -> bf16 out ----------------
__global__ __launch_bounds__(256) void ln_kernel(const float* __restrict__ x,
                                                 const float* __restrict__ g,
                                                 const float* __restrict__ bb,
                                                 unsigned short* __restrict__ out) {
    const int row = blockIdx.x;
    const int tid = threadIdx.x;
    const float4 v = ((const float4*)(x + (size_t)row * 1024))[tid];
    float s = v.x + v.y + v.z + v.w;
    float q = v.x * v.x + v.y * v.y + v.z * v.z + v.w * v.w;
#pragma unroll
    for (int d = 1; d < 64; d <<= 1) {
        s += __shfl_xor(s, d, 64);
        q += __shfl_xor(q, d, 64);
    }
    __shared__ float ss[4], sq[4];
    const int wv = tid >> 6;
    if ((tid & 63) == 0) { ss[wv] = s; sq[wv] = q; }
    __syncthreads();
    s = ss[0] + ss[1] + ss[2] + ss[3];
    q = sq[0] + sq[1] + sq[2] + sq[3];
    const float mu = s * (1.0f / 1024.0f);
    const float var = q * (1.0f / 1024.0f) - mu * mu;
    const float rs = rsqrtf(var + 1e-5f);
    const int c = tid * 4;
    ushort4 o;
    o.x = f2bf((v.x - mu) * rs * g[c + 0] + bb[c + 0]);
    o.y = f2bf((v.y - mu) * rs * g[c + 1] + bb[c + 1]);
    o.z = f2bf((v.z - mu) * rs * g[c + 2] + bb[c + 2]);
    o.w = f2bf((v.w - mu) * rs * g[c + 3] + bb[c + 3]);
    *(ushort4*)&out[(size_t)row * 1024 + c] = o;
}

// ---------------- GEMM: C[M,N] = A[M,K] * Bw[N,K]^T  (both bf16 K-contiguous) ----------
// MODE 0: out bf16, plain.  MODE 1: out f32 = acc + bias[n] + res[m,n].
// MODE 2: out bf16 = gelu_exact(acc + bias[n]).
template <int MODE>
__global__ __launch_bounds__(256) void gemm_bt(const unsigned short* __restrict__ A,
                                               const unsigned short* __restrict__ Bw,
                                               void* __restrict__ Out,
                                               const float* __restrict__ bias,
                                               const float* __restrict__ res,
                                               int M, int N, int K) {
    __shared__ unsigned short As[128][32];
    __shared__ unsigned short Bs[128][32];
    const int tid = threadIdx.x;
    const int lane = tid & 63;
    const int wave = tid >> 6;
    const int wm = wave >> 1, wn = wave & 1;
    const int m0 = blockIdx.y * 128;
    const int n0 = blockIdx.x * 128;

    f32x4 acc[4][4] = {};

    const int lrow = lane >> 2;       // 0..15
    const int lcol = (lane & 3) * 8;  // 0,8,16,24

    for (int k0 = 0; k0 < K; k0 += 32) {
#pragma unroll
        for (int c = 0; c < 2; ++c) {
            const int r0 = c * 64 + wave * 16;
            gload_lds16(A + (size_t)(m0 + r0 + lrow) * K + k0 + lcol, &As[r0][0]);
            gload_lds16(Bw + (size_t)(n0 + r0 + lrow) * K + k0 + lcol, &Bs[r0][0]);
        }
        __syncthreads();
        const int fr = lane & 15, fc = (lane >> 4) * 8;
        bf16x8 af[4], bfr[4];
#pragma unroll
        for (int mt = 0; mt < 4; ++mt) af[mt] = *(const bf16x8*)&As[wm * 64 + mt * 16 + fr][fc];
#pragma unroll
        for (int nt = 0; nt < 4; ++nt) bfr[nt] = *(const bf16x8*)&Bs[wn * 64 + nt * 16 + fr][fc];
#pragma unroll
        for (int mt = 0; mt < 4; ++mt)
#pragma unroll
            for (int nt = 0; nt < 4; ++nt)
                acc[mt][nt] = __builtin_amdgcn_mfma_f32_16x16x32_bf16(af[mt], bfr[nt], acc[mt][nt], 0, 0, 0);
        __syncthreads();
    }

    const int rr = (lane >> 4) * 4;
    const int cc = lane & 15;
#pragma unroll
    for (int mt = 0; mt < 4; ++mt) {
#pragma unroll
        for (int nt = 0; nt < 4; ++nt) {
            const int col = n0 + wn * 64 + nt * 16 + cc;
#pragma unroll
            for (int r = 0; r < 4; ++r) {
                const int row = m0 + wm * 64 + mt * 16 + rr + r;
                const float v = acc[mt][nt][r];
                if (MODE == 0) {
                    ((unsigned short*)Out)[(size_t)row * N + col] = f2bf(v);
                } else if (MODE == 1) {
                    ((float*)Out)[(size_t)row * N + col] =
                        v + bias[col] + res[(size_t)row * N + col];
                } else {
                    const float t = v + bias[col];
                    const float ge = 0.5f * t * (1.0f + erff(t * 0.70710678118654752f));
                    ((unsigned short*)Out)[(size_t)row * N + col] = f2bf(ge);
                }
            }
        }
    }
}

// ---------------- Flash attention ----------------
// grid: 2048 blocks = qt(16) x h(16) x b(8); 256 threads = 4 waves x 16 q-rows.
__global__ __launch_bounds__(256) void attn_kernel(const unsigned short* __restrict__ qkv,
                                                   const int* __restrict__ length,
                                                   unsigned short* __restrict__ y) {
    const int bid = blockIdx.x;
    const int qt = bid & 15;
    const int h = (bid >> 4) & 15;
    const int b = bid >> 8;
    const int tid = threadIdx.x, lane = tid & 63, w = tid >> 6;
    const int q0 = qt * 64;
    const int len = length[b];

    __shared__ unsigned short Kt[32][64];
    __shared__ unsigned short VT[64][32];
    __shared__ unsigned short Pl[4][16][32];

    const int fr = lane & 15, kg = lane >> 4;

    bf16x8 qf[2];
    {
        const unsigned short* qbase = qkv + (size_t)(b * Nn + q0 + w * 16 + fr) * 3072 + h * 64;
        qf[0] = *(const bf16x8*)(qbase + kg * 8);
        qf[1] = *(const bf16x8*)(qbase + 32 + kg * 8);
    }

    float m[4] = {-1e30f, -1e30f, -1e30f, -1e30f};
    float lsum[4] = {0.f, 0.f, 0.f, 0.f};
    f32x4 accO[4] = {};

    const int srow = tid >> 3;        // 0..31
    const int scol = (tid & 7) * 8;   // 0..56

    for (int kv0 = 0; kv0 < Nn; kv0 += 32) {
        {
            const unsigned short* gk =
                qkv + (size_t)(b * Nn + kv0 + srow) * 3072 + 1024 + h * 64 + scol;
            *(uint4*)&Kt[srow][scol] = *(const uint4*)gk;
            const unsigned short* gv =
                qkv + (size_t)(b * Nn + kv0 + srow) * 3072 + 2048 + h * 64 + scol;
            uint4 vv = *(const uint4*)gv;
            const unsigned short* pv = (const unsigned short*)&vv;
#pragma unroll
            for (int i = 0; i < 8; ++i) VT[scol + i][srow] = pv[i];
        }
        __syncthreads();

        f32x4 accS[2] = {};
#pragma unroll
        for (int nt = 0; nt < 2; ++nt)
#pragma unroll
            for (int kt = 0; kt < 2; ++kt) {
                bf16x8 kf = *(const bf16x8*)&Kt[nt * 16 + fr][kt * 32 + kg * 8];
                accS[nt] = __builtin_amdgcn_mfma_f32_16x16x32_bf16(qf[kt], kf, accS[nt], 0, 0, 0);
            }

        float p[2][4], sc[4];
#pragma unroll
        for (int r = 0; r < 4; ++r) {
            float s0 = accS[0][r] * SCALEf + ((kv0 + fr >= len) ? -10000.0f : 0.0f);
            float s1 = accS[1][r] * SCALEf + ((kv0 + 16 + fr >= len) ? -10000.0f : 0.0f);
            float mx = fmaxf(s0, s1);
#pragma unroll
            for (int d = 1; d < 16; d <<= 1) mx = fmaxf(mx, __shfl_xor(mx, d, 64));
            const float mnew = fmaxf(m[r], mx);
            sc[r] = __expf(m[r] - mnew);
            const float e0 = __expf(s0 - mnew);
            const float e1 = __expf(s1 - mnew);
            p[0][r] = e0; p[1][r] = e1;
            float rsum = e0 + e1;
#pragma unroll
            for (int d = 1; d < 16; d <<= 1) rsum += __shfl_xor(rsum, d, 64);
            lsum[r] = lsum[r] * sc[r] + rsum;
            m[r] = mnew;
        }
#pragma unroll
        for (int nd = 0; nd < 4; ++nd)
#pragma unroll
            for (int r = 0; r < 4; ++r) accO[nd][r] *= sc[r];

#pragma unroll
        for (int nt = 0; nt < 2; ++nt)
#pragma unroll
            for (int r = 0; r < 4; ++r)
                Pl[w][kg * 4 + r][nt * 16 + fr] = f2bf(p[nt][r]);
        __builtin_amdgcn_wave_barrier();

        bf16x8 pf = *(const bf16x8*)&Pl[w][fr][kg * 8];
#pragma unroll
        for (int nd = 0; nd < 4; ++nd) {
            bf16x8 vf = *(const bf16x8*)&VT[nd * 16 + fr][kg * 8];
            accO[nd] = __builtin_amdgcn_mfma_f32_16x16x32_bf16(pf, vf, accO[nd], 0, 0, 0);
        }
        __syncthreads();
    }

#pragma unroll
    for (int r = 0; r < 4; ++r) {
        const float inv = 1.0f / lsum[r];
        const int row = q0 + w * 16 + kg * 4 + r;
#pragma unroll
        for (int nd = 0; nd < 4; ++nd)
            y[(size_t)(b * Nn + row) * 1024 + h * 64 + nd * 16 + fr] = f2bf(accO[nd][r] * inv);
    }
}

// ---------------- launch ----------------
extern "C" void kernel_launch(void* const* d_in, const int* in_sizes, int n_in,
                              void* d_out, int out_size, void* d_ws, size_t ws_size,
                              hipStream_t stream) {
    (void)in_sizes; (void)n_in; (void)out_size; (void)ws_size;
    const float* x     = (const float*)d_in[0];
    const int*   len   = (const int*)d_in[1];
    const float* g1    = (const float*)d_in[2];
    const float* b1    = (const float*)d_in[3];
    const float* Wqkv  = (const float*)d_in[4];
    const float* Wproj = (const float*)d_in[5];
    const float* bproj = (const float*)d_in[6];
    const float* g2    = (const float*)d_in[7];
    const float* b2    = (const float*)d_in[8];
    const float* W1    = (const float*)d_in[9];
    const float* bb1   = (const float*)d_in[10];
    const float* W2    = (const float*)d_in[11];
    const float* bb2   = (const float*)d_in[12];
    float* out = (float*)d_out;

    char* ws = (char*)d_ws;
    size_t off = 0;
    auto alloc = [&](size_t bytes) {
        void* p = ws + off;
        off += (bytes + 255) & ~(size_t)255;
        return p;
    };
    unsigned short* xn  = (unsigned short*)alloc(8192ULL * 1024 * 2);  // reused for xn1, xn2
    unsigned short* qkv = (unsigned short*)alloc(8192ULL * 3072 * 2);  // later reused as h (first 50MB)
    unsigned short* yb  = (unsigned short*)alloc(8192ULL * 1024 * 2);  // h tail overlaps this
    float* x2           = (float*)alloc(8192ULL * 1024 * 4);
    unsigned short* wqkv_b  = (unsigned short*)alloc(3072ULL * 1024 * 2);
    unsigned short* wproj_b = (unsigned short*)alloc(1024ULL * 1024 * 2);
    unsigned short* w1_b    = (unsigned short*)alloc(4096ULL * 1024 * 2);
    unsigned short* w2_b    = (unsigned short*)alloc(1024ULL * 4096 * 2);
    unsigned short* hb = qkv;  // 8192*4096*2 = qkv(8192*3072*2) + yb(8192*1024*2), both dead by then

    cvt_bf16<<<3072 * 1024 / 4 / 256, 256, 0, stream>>>(Wqkv, wqkv_b, 3072 * 1024 / 4);
    cvt_bf16<<<1024 * 1024 / 4 / 256, 256, 0, stream>>>(Wproj, wproj_b, 1024 * 1024 / 4);
    cvt_bf16<<<4096 * 1024 / 4 / 256, 256, 0, stream>>>(W1, w1_b, 4096 * 1024 / 4);
    cvt_bf16<<<4096 * 1024 / 4 / 256, 256, 0, stream>>>(W2, w2_b, 4096 * 1024 / 4);

    // LN1: x -> xn (bf16)
    ln_kernel<<<8192, 256, 0, stream>>>(x, g1, b1, xn);
    // QKV: [8192,1024] x [3072,1024]^T -> qkv bf16
    gemm_bt<0><<<dim3(3072 / 128, 8192 / 128), 256, 0, stream>>>(xn, wqkv_b, qkv, nullptr, nullptr,
                                                                 8192, 3072, 1024);
    // attention -> yb bf16
    attn_kernel<<<2048, 256, 0, stream>>>(qkv, len, yb);
    // proj + bias + residual(x) -> x2 f32
    gemm_bt<1><<<dim3(1024 / 128, 8192 / 128), 256, 0, stream>>>(yb, wproj_b, x2, bproj, x,
                                                                 8192, 1024, 1024);
    // LN2: x2 -> xn (bf16)
    ln_kernel<<<8192, 256, 0, stream>>>(x2, g2, b2, xn);
    // MLP1 + bias + gelu -> hb bf16
    gemm_bt<2><<<dim3(4096 / 128, 8192 / 128), 256, 0, stream>>>(xn, w1_b, hb, bb1, nullptr,
                                                                 8192, 4096, 1024);
    // MLP2 + bias + residual(x2) -> out f32
    gemm_bt<1><<<dim3(1024 / 128, 8192 / 128), 256, 0, stream>>>(hb, w2_b, out, bb2, x2,
                                                                 8192, 1024, 4096);
}

// Round 2
// 464.662 us; speedup vs baseline: 1.2478x; 1.2478x over previous
//
#include <hip/hip_runtime.h>
#include <math.h>

#define Bn 8
#define Nn 1024
#define Cn 1024
#define Hn 16
#define Dn 64
#define HIDn 4096
#define SCALEf 0.125f

typedef __bf16 bf16x8 __attribute__((ext_vector_type(8)));
typedef float f32x4 __attribute__((ext_vector_type(4)));

__device__ inline unsigned short f2bf(float f) {
    union { float f; unsigned int u; } v; v.f = f;
    unsigned int r = v.u + 0x7fffu + ((v.u >> 16) & 1u);
    return (unsigned short)(r >> 16);
}

__device__ inline void gload_lds16(const void* g, void* l) {
    auto gp = reinterpret_cast<const unsigned int __attribute__((address_space(1)))*>(
        reinterpret_cast<uintptr_t>(g));
    auto lp = reinterpret_cast<unsigned int __attribute__((address_space(3)))*>(
        reinterpret_cast<uintptr_t>(l));
    __builtin_amdgcn_global_load_lds(gp, lp, 16, 0, 0);
}

// ---------------- f32 -> bf16 conversion ----------------
__global__ __launch_bounds__(256) void cvt_bf16(const float* __restrict__ in,
                                                unsigned short* __restrict__ out, int n4) {
    int i = blockIdx.x * 256 + threadIdx.x;
    if (i < n4) {
        float4 v = ((const float4*)in)[i];
        ushort4 o;
        o.x = f2bf(v.x); o.y = f2bf(v.y); o.z = f2bf(v.z); o.w = f2bf(v.w);
        ((ushort4*)out)[i] = o;
    }
}

// ---------------- LayerNorm (C=1024), fp32 in -> bf16 out ----------------
__global__ __launch_bounds__(256) void ln_kernel(const float* __restrict__ x,
                                                 const float* __restrict__ g,
                                                 const float* __restrict__ bb,
                                                 unsigned short* __restrict__ out) {
    const int row = blockIdx.x;
    const int tid = threadIdx.x;
    const float4 v = ((const float4*)(x + (size_t)row * 1024))[tid];
    float s = v.x + v.y + v.z + v.w;
    float q = v.x * v.x + v.y * v.y + v.z * v.z + v.w * v.w;
#pragma unroll
    for (int d = 1; d < 64; d <<= 1) {
        s += __shfl_xor(s, d, 64);
        q += __shfl_xor(q, d, 64);
    }
    __shared__ float ss[4], sq[4];
    const int wv = tid >> 6;
    if ((tid & 63) == 0) { ss[wv] = s; sq[wv] = q; }
    __syncthreads();
    s = ss[0] + ss[1] + ss[2] + ss[3];
    q = sq[0] + sq[1] + sq[2] + sq[3];
    const float mu = s * (1.0f / 1024.0f);
    const float var = q * (1.0f / 1024.0f) - mu * mu;
    const float rs = rsqrtf(var + 1e-5f);
    const int c = tid * 4;
    ushort4 o;
    o.x = f2bf((v.x - mu) * rs * g[c + 0] + bb[c + 0]);
    o.y = f2bf((v.y - mu) * rs * g[c + 1] + bb[c + 1]);
    o.z = f2bf((v.z - mu) * rs * g[c + 2] + bb[c + 2]);
    o.w = f2bf((v.w - mu) * rs * g[c + 3] + bb[c + 3]);
    *(ushort4*)&out[(size_t)row * 1024 + c] = o;
}

// ---------------- GEMM: C[M,N] = A[M,K] * Bw[N,K]^T  (both bf16 K-contiguous) ----------
// MODE 0: out bf16, plain.  MODE 1: out f32 = acc + bias[n] + res[m,n].
// MODE 2: out bf16 = gelu_exact(acc + bias[n]).
template <int MODE>
__global__ __launch_bounds__(256) void gemm_bt(const unsigned short* __restrict__ A,
                                               const unsigned short* __restrict__ Bw,
                                               void* __restrict__ Out,
                                               const float* __restrict__ bias,
                                               const float* __restrict__ res,
                                               int M, int N, int K, int gx) {
    __shared__ unsigned short As[128][32];
    __shared__ unsigned short Bs[128][32];
    const int tid = threadIdx.x;
    const int lane = tid & 63;
    const int wave = tid >> 6;
    const int wm = wave >> 1, wn = wave & 1;
    // XCD-aware bijective swizzle (all grids are multiples of 8)
    const int nwg = gridDim.x;
    const int sw = (blockIdx.x & 7) * (nwg >> 3) + (blockIdx.x >> 3);
    const int m0 = (sw / gx) * 128;
    const int n0 = (sw % gx) * 128;

    f32x4 acc[4][4] = {};

    const int lrow = lane >> 2;       // 0..15
    const int lcol = (lane & 3) * 8;  // 0,8,16,24

    for (int k0 = 0; k0 < K; k0 += 32) {
#pragma unroll
        for (int c = 0; c < 2; ++c) {
            const int r0 = c * 64 + wave * 16;
            gload_lds16(A + (size_t)(m0 + r0 + lrow) * K + k0 + lcol, &As[r0][0]);
            gload_lds16(Bw + (size_t)(n0 + r0 + lrow) * K + k0 + lcol, &Bs[r0][0]);
        }
        __syncthreads();
        const int fr = lane & 15, fc = (lane >> 4) * 8;
        bf16x8 af[4], bfr[4];
#pragma unroll
        for (int mt = 0; mt < 4; ++mt) af[mt] = *(const bf16x8*)&As[wm * 64 + mt * 16 + fr][fc];
#pragma unroll
        for (int nt = 0; nt < 4; ++nt) bfr[nt] = *(const bf16x8*)&Bs[wn * 64 + nt * 16 + fr][fc];
#pragma unroll
        for (int mt = 0; mt < 4; ++mt)
#pragma unroll
            for (int nt = 0; nt < 4; ++nt)
                acc[mt][nt] = __builtin_amdgcn_mfma_f32_16x16x32_bf16(af[mt], bfr[nt], acc[mt][nt], 0, 0, 0);
        __syncthreads();
    }

    const int rr = (lane >> 4) * 4;
    const int cc = lane & 15;
#pragma unroll
    for (int mt = 0; mt < 4; ++mt) {
#pragma unroll
        for (int nt = 0; nt < 4; ++nt) {
            const int col = n0 + wn * 64 + nt * 16 + cc;
#pragma unroll
            for (int r = 0; r < 4; ++r) {
                const int row = m0 + wm * 64 + mt * 16 + rr + r;
                const float v = acc[mt][nt][r];
                if (MODE == 0) {
                    ((unsigned short*)Out)[(size_t)row * N + col] = f2bf(v);
                } else if (MODE == 1) {
                    ((float*)Out)[(size_t)row * N + col] =
                        v + bias[col] + res[(size_t)row * N + col];
                } else {
                    const float t = v + bias[col];
                    const float ge = 0.5f * t * (1.0f + erff(t * 0.70710678118654752f));
                    ((unsigned short*)Out)[(size_t)row * N + col] = f2bf(ge);
                }
            }
        }
    }
}

// ---------------- Flash attention v2 ----------------
// grid: 2048 blocks (XCD-swizzled) = qt(16) x h(16) x b(8); 256 threads = 4 waves x 16 q-rows.
// KVBLK=64; K staged via global_load_lds with pre-swizzled source; V reg-staged transposed;
// all LDS tiles XOR-swizzled with swz(row)=((row^(row>>3))&7)<<4 on write AND read.
__global__ __launch_bounds__(256) void attn_kernel(const unsigned short* __restrict__ qkv,
                                                   const int* __restrict__ length,
                                                   unsigned short* __restrict__ y) {
    const int id2 = (blockIdx.x & 7) * 256 + (blockIdx.x >> 3);  // XCD swizzle (2048/8=256)
    const int qt = id2 & 15;
    const int h = (id2 >> 4) & 15;
    const int b = id2 >> 8;
    const int tid = threadIdx.x, lane = tid & 63, w = tid >> 6;
    const int q0 = qt * 64;
    const int len = length[b];
    const int ntiles = (len + 63) >> 6;

    __shared__ unsigned short Ks[64 * 64];   // [k][d] row 128B, swizzled
    __shared__ unsigned short Vs[64 * 64];   // [d][k] row 128B, swizzled  (V transposed)
    __shared__ unsigned short Ps[4 * 16 * 64];  // per-wave [q][k] row 128B, swizzled

    const int fr = lane & 15, kg = lane >> 4;

    // Q fragments (A operand): row q = w*16+fr, d = kt*32 + kg*8 + j
    bf16x8 qf[2];
    {
        const unsigned short* qb = qkv + (size_t)(b * Nn + q0 + w * 16 + fr) * 3072 + h * 64 + kg * 8;
        qf[0] = *(const bf16x8*)(qb);
        qf[1] = *(const bf16x8*)(qb + 32);
    }

    float m[4] = {-1e30f, -1e30f, -1e30f, -1e30f};
    float lsum[4] = {0.f, 0.f, 0.f, 0.f};
    f32x4 accO[4] = {};

    // K staging geometry (per wave, 2 calls of 8 rows each)
    const int krow_l = lane >> 3;  // 0..7
    const int kslot = lane & 7;    // 16B slot in 128B row
    // V staging geometry: thread covers rows vk0,vk0+1, cols vd0..vd0+7
    const int vk0 = (tid >> 3) * 2;
    const int vd0 = (tid & 7) * 8;
    const unsigned short* vbase = qkv + (size_t)(b * Nn) * 3072 + 2048 + h * 64 + vd0;

    for (int t = 0; t < ntiles; ++t) {
        const int kv0 = t << 6;
        // --- stage K: async global->LDS, source pre-swizzled so swizzled reads are correct
#pragma unroll
        for (int c = 0; c < 2; ++c) {
            const int k = c * 32 + w * 8 + krow_l;
            const int ss = kslot ^ ((k ^ (k >> 3)) & 7);
            gload_lds16(qkv + (size_t)(b * Nn + kv0 + k) * 3072 + 1024 + h * 64 + ss * 8,
                        &Ks[(c * 32 + w * 8) * 64]);
        }
        // --- stage V transposed: 2 row-loads, pack k-pairs, swizzled ds_write_b32
        {
            uint4 v0 = *(const uint4*)(vbase + (size_t)(kv0 + vk0) * 3072);
            uint4 v1 = *(const uint4*)(vbase + (size_t)(kv0 + vk0 + 1) * 3072);
            const unsigned* a0 = (const unsigned*)&v0;
            const unsigned* a1 = (const unsigned*)&v1;
#pragma unroll
            for (int i = 0; i < 8; ++i) {
                const unsigned lo = (a0[i >> 1] >> ((i & 1) * 16)) & 0xffffu;
                const unsigned hi = (a1[i >> 1] >> ((i & 1) * 16)) & 0xffffu;
                const int d = vd0 + i;
                const int off = (d * 128 + vk0 * 2) ^ (((d ^ (d >> 3)) & 7) << 4);
                *(unsigned*)((char*)Vs + off) = lo | (hi << 16);
            }
        }
        __syncthreads();

        // --- QK^T: accS[nt] covers k-cols nt*16..+15
        f32x4 accS[4] = {};
#pragma unroll
        for (int nt = 0; nt < 4; ++nt) {
            const int kr = nt * 16 + fr;
            const int swz = ((kr ^ (kr >> 3)) & 7) << 4;
#pragma unroll
            for (int kt = 0; kt < 2; ++kt) {
                bf16x8 kf = *(const bf16x8*)((const char*)Ks + ((kr * 128 + (kt * 32 + kg * 8) * 2) ^ swz));
                accS[nt] = __builtin_amdgcn_mfma_f32_16x16x32_bf16(qf[kt], kf, accS[nt], 0, 0, 0);
            }
        }

        // --- online softmax (rows q = kg*4+r, reduce over fr lanes)
        float p[4][4], sc[4];
#pragma unroll
        for (int r = 0; r < 4; ++r) {
            float sv[4];
            float mx = -1e30f;
#pragma unroll
            for (int nt = 0; nt < 4; ++nt) {
                sv[nt] = accS[nt][r] * SCALEf + ((kv0 + nt * 16 + fr >= len) ? -10000.0f : 0.0f);
                mx = fmaxf(mx, sv[nt]);
            }
#pragma unroll
            for (int d = 1; d < 16; d <<= 1) mx = fmaxf(mx, __shfl_xor(mx, d, 64));
            const float mnew = fmaxf(m[r], mx);
            sc[r] = __expf(m[r] - mnew);
            float rsum = 0.f;
#pragma unroll
            for (int nt = 0; nt < 4; ++nt) {
                p[nt][r] = __expf(sv[nt] - mnew);
                rsum += p[nt][r];
            }
#pragma unroll
            for (int d = 1; d < 16; d <<= 1) rsum += __shfl_xor(rsum, d, 64);
            lsum[r] = lsum[r] * sc[r] + rsum;
            m[r] = mnew;
        }
#pragma unroll
        for (int nd = 0; nd < 4; ++nd)
#pragma unroll
            for (int r = 0; r < 4; ++r) accO[nd][r] *= sc[r];

        // --- write P (bf16) to per-wave LDS, swizzled rows
#pragma unroll
        for (int r = 0; r < 4; ++r) {
            const int q = kg * 4 + r;
            const int swz = ((q ^ (q >> 3)) & 7) << 4;
#pragma unroll
            for (int nt = 0; nt < 4; ++nt) {
                const int kk = nt * 16 + fr;
                *(unsigned short*)((char*)Ps + ((w * 2048 + q * 128 + kk * 2) ^ swz)) = f2bf(p[nt][r]);
            }
        }
        __builtin_amdgcn_wave_barrier();

        // --- PV: A = P (rows q), B = V^T (cols d)
        const int swzp = ((fr ^ (fr >> 3)) & 7) << 4;
#pragma unroll
        for (int kt = 0; kt < 2; ++kt) {
            bf16x8 pf = *(const bf16x8*)((const char*)Ps +
                        ((w * 2048 + fr * 128 + (kt * 32 + kg * 8) * 2) ^ swzp));
#pragma unroll
            for (int nd = 0; nd < 4; ++nd) {
                const int d = nd * 16 + fr;
                const int swzv = ((d ^ (d >> 3)) & 7) << 4;
                bf16x8 vf = *(const bf16x8*)((const char*)Vs +
                            ((d * 128 + (kt * 32 + kg * 8) * 2) ^ swzv));
                accO[nd] = __builtin_amdgcn_mfma_f32_16x16x32_bf16(pf, vf, accO[nd], 0, 0, 0);
            }
        }
        __syncthreads();
    }

#pragma unroll
    for (int r = 0; r < 4; ++r) {
        const float inv = 1.0f / lsum[r];
        const int row = q0 + w * 16 + kg * 4 + r;
#pragma unroll
        for (int nd = 0; nd < 4; ++nd)
            y[(size_t)(b * Nn + row) * 1024 + h * 64 + nd * 16 + fr] = f2bf(accO[nd][r] * inv);
    }
}

// ---------------- launch ----------------
extern "C" void kernel_launch(void* const* d_in, const int* in_sizes, int n_in,
                              void* d_out, int out_size, void* d_ws, size_t ws_size,
                              hipStream_t stream) {
    (void)in_sizes; (void)n_in; (void)out_size; (void)ws_size;
    const float* x     = (const float*)d_in[0];
    const int*   len   = (const int*)d_in[1];
    const float* g1    = (const float*)d_in[2];
    const float* b1    = (const float*)d_in[3];
    const float* Wqkv  = (const float*)d_in[4];
    const float* Wproj = (const float*)d_in[5];
    const float* bproj = (const float*)d_in[6];
    const float* g2    = (const float*)d_in[7];
    const float* b2    = (const float*)d_in[8];
    const float* W1    = (const float*)d_in[9];
    const float* bb1   = (const float*)d_in[10];
    const float* W2    = (const float*)d_in[11];
    const float* bb2   = (const float*)d_in[12];
    float* out = (float*)d_out;

    char* ws = (char*)d_ws;
    size_t off = 0;
    auto alloc = [&](size_t bytes) {
        void* p = ws + off;
        off += (bytes + 255) & ~(size_t)255;
        return p;
    };
    unsigned short* xn  = (unsigned short*)alloc(8192ULL * 1024 * 2);  // reused for xn1, xn2
    unsigned short* qkv = (unsigned short*)alloc(8192ULL * 3072 * 2);  // later reused as h (first 50MB)
    unsigned short* yb  = (unsigned short*)alloc(8192ULL * 1024 * 2);  // h tail overlaps this
    float* x2           = (float*)alloc(8192ULL * 1024 * 4);
    unsigned short* wqkv_b  = (unsigned short*)alloc(3072ULL * 1024 * 2);
    unsigned short* wproj_b = (unsigned short*)alloc(1024ULL * 1024 * 2);
    unsigned short* w1_b    = (unsigned short*)alloc(4096ULL * 1024 * 2);
    unsigned short* w2_b    = (unsigned short*)alloc(1024ULL * 4096 * 2);
    unsigned short* hb = qkv;  // 8192*4096*2 = qkv(8192*3072*2) + yb(8192*1024*2), both dead by then

    cvt_bf16<<<3072 * 1024 / 4 / 256, 256, 0, stream>>>(Wqkv, wqkv_b, 3072 * 1024 / 4);
    cvt_bf16<<<1024 * 1024 / 4 / 256, 256, 0, stream>>>(Wproj, wproj_b, 1024 * 1024 / 4);
    cvt_bf16<<<4096 * 1024 / 4 / 256, 256, 0, stream>>>(W1, w1_b, 4096 * 1024 / 4);
    cvt_bf16<<<4096 * 1024 / 4 / 256, 256, 0, stream>>>(W2, w2_b, 4096 * 1024 / 4);

    // LN1: x -> xn (bf16)
    ln_kernel<<<8192, 256, 0, stream>>>(x, g1, b1, xn);
    // QKV: [8192,1024] x [3072,1024]^T -> qkv bf16
    gemm_bt<0><<<(3072 / 128) * (8192 / 128), 256, 0, stream>>>(xn, wqkv_b, qkv, nullptr, nullptr,
                                                                8192, 3072, 1024, 3072 / 128);
    // attention -> yb bf16
    attn_kernel<<<2048, 256, 0, stream>>>(qkv, len, yb);
    // proj + bias + residual(x) -> x2 f32
    gemm_bt<1><<<(1024 / 128) * (8192 / 128), 256, 0, stream>>>(yb, wproj_b, x2, bproj, x,
                                                                8192, 1024, 1024, 1024 / 128);
    // LN2: x2 -> xn (bf16)
    ln_kernel<<<8192, 256, 0, stream>>>(x2, g2, b2, xn);
    // MLP1 + bias + gelu -> hb bf16
    gemm_bt<2><<<(4096 / 128) * (8192 / 128), 256, 0, stream>>>(xn, w1_b, hb, bb1, nullptr,
                                                                8192, 4096, 1024, 4096 / 128);
    // MLP2 + bias + residual(x2) -> out f32
    gemm_bt<1><<<(1024 / 128) * (8192 / 128), 256, 0, stream>>>(hb, w2_b, out, bb2, x2,
                                                                8192, 1024, 4096, 1024 / 128);
}

// Round 3
// 396.627 us; speedup vs baseline: 1.4619x; 1.1715x over previous
//
#include <hip/hip_runtime.h>
#include <math.h>

#define Bn 8
#define Nn 1024
#define Cn 1024
#define Hn 16
#define Dn 64
#define HIDn 4096
#define SCALEf 0.125f

typedef __bf16 bf16x8 __attribute__((ext_vector_type(8)));
typedef float f32x4 __attribute__((ext_vector_type(4)));

__device__ inline unsigned short f2bf(float f) {
    union { float f; unsigned int u; } v; v.f = f;
    unsigned int r = v.u + 0x7fffu + ((v.u >> 16) & 1u);
    return (unsigned short)(r >> 16);
}

__device__ inline void gload_lds16(const void* g, void* l) {
    auto gp = reinterpret_cast<const unsigned int __attribute__((address_space(1)))*>(
        reinterpret_cast<uintptr_t>(g));
    auto lp = reinterpret_cast<unsigned int __attribute__((address_space(3)))*>(
        reinterpret_cast<uintptr_t>(l));
    __builtin_amdgcn_global_load_lds(gp, lp, 16, 0, 0);
}

// ---------------- f32 -> bf16 conversion ----------------
__global__ __launch_bounds__(256) void cvt_bf16(const float* __restrict__ in,
                                                unsigned short* __restrict__ out, int n4) {
    int i = blockIdx.x * 256 + threadIdx.x;
    if (i < n4) {
        float4 v = ((const float4*)in)[i];
        ushort4 o;
        o.x = f2bf(v.x); o.y = f2bf(v.y); o.z = f2bf(v.z); o.w = f2bf(v.w);
        ((ushort4*)out)[i] = o;
    }
}

// ---------------- LayerNorm (C=1024), fp32 in -> bf16 out ----------------
__global__ __launch_bounds__(256) void ln_kernel(const float* __restrict__ x,
                                                 const float* __restrict__ g,
                                                 const float* __restrict__ bb,
                                                 unsigned short* __restrict__ out) {
    const int row = blockIdx.x;
    const int tid = threadIdx.x;
    const float4 v = ((const float4*)(x + (size_t)row * 1024))[tid];
    float s = v.x + v.y + v.z + v.w;
    float q = v.x * v.x + v.y * v.y + v.z * v.z + v.w * v.w;
#pragma unroll
    for (int d = 1; d < 64; d <<= 1) {
        s += __shfl_xor(s, d, 64);
        q += __shfl_xor(q, d, 64);
    }
    __shared__ float ss[4], sq[4];
    const int wv = tid >> 6;
    if ((tid & 63) == 0) { ss[wv] = s; sq[wv] = q; }
    __syncthreads();
    s = ss[0] + ss[1] + ss[2] + ss[3];
    q = sq[0] + sq[1] + sq[2] + sq[3];
    const float mu = s * (1.0f / 1024.0f);
    const float var = q * (1.0f / 1024.0f) - mu * mu;
    const float rs = rsqrtf(var + 1e-5f);
    const int c = tid * 4;
    ushort4 o;
    o.x = f2bf((v.x - mu) * rs * g[c + 0] + bb[c + 0]);
    o.y = f2bf((v.y - mu) * rs * g[c + 1] + bb[c + 1]);
    o.z = f2bf((v.z - mu) * rs * g[c + 2] + bb[c + 2]);
    o.w = f2bf((v.w - mu) * rs * g[c + 3] + bb[c + 3]);
    *(ushort4*)&out[(size_t)row * 1024 + c] = o;
}

// ---------------- GEMM v2: C[M,N] = A[M,K] * Bw[N,K]^T, 256xBN tile, BK=64 ----------
// 8 waves (512 thr), double-buffered LDS, prefetch-early 2-phase loop.
// LDS rows linear [r][64], 16B slot s of row r holds global slot s^(r&7)
// (pre-swizzled global_load_lds source); fragment reads apply the same XOR ->
// 2-way (free) bank aliasing only.
// MODE 0: out bf16. MODE 1: out f32 = acc + bias[n] + res. MODE 2: bf16 gelu(acc+bias).
template <int MODE, int BN>
__global__ __launch_bounds__(512, 2) void gemm2(const unsigned short* __restrict__ A,
                                                const unsigned short* __restrict__ Bw,
                                                void* __restrict__ Out,
                                                const float* __restrict__ bias,
                                                const float* __restrict__ res,
                                                int M, int N, int K, int gn) {
    constexpr int WN = BN / 64;       // waves along N: 4 (BN=256) or 2 (BN=128)
    constexpr int WM = 8 / WN;        // waves along M: 2 or 4
    constexpr int MFM = 256 / WM / 16;  // m-frags per wave: 8 or 4
    constexpr int RB = BN / 64;       // B stage rounds (64 rows per round)
    constexpr int ASZ = 256 * 64;
    constexpr int BSZ = BN * 64;
    __shared__ unsigned short lds[2 * (ASZ + BSZ)];

    const int tid = threadIdx.x;
    const int l = tid & 63, w = tid >> 6;
    const int nwg = gridDim.x;
    const int sw = (blockIdx.x & 7) * (nwg >> 3) + (blockIdx.x >> 3);  // XCD swizzle
    const int m0 = (sw / gn) * 256;
    const int n0 = (sw % gn) * BN;
    const int wm = w / WN, wn = w % WN;
    const int fr = l & 15, kg = l >> 4;
    const int sr = l >> 3, sslot = l & 7;  // staging row-in-stripe / slot

    auto stage = [&](int bufi, int k0) {
        unsigned short* dA = lds + bufi * (ASZ + BSZ);
        unsigned short* dB = dA + ASZ;
#pragma unroll
        for (int j = 0; j < 4; ++j) {
            const int r = j * 64 + w * 8 + sr;
            gload_lds16(A + (size_t)(m0 + r) * K + k0 + ((sslot ^ (r & 7)) * 8),
                        dA + (j * 64 + w * 8) * 64);
        }
#pragma unroll
        for (int j = 0; j < RB; ++j) {
            const int r = j * 64 + w * 8 + sr;
            gload_lds16(Bw + (size_t)(n0 + r) * K + k0 + ((sslot ^ (r & 7)) * 8),
                        dB + (j * 64 + w * 8) * 64);
        }
    };

    f32x4 acc[MFM][4] = {};

    const int NT = K >> 6;
    int cur = 0;
    stage(0, 0);
    __syncthreads();  // compiler drains vmcnt(0) before the barrier

    for (int t = 0; t < NT; ++t) {
        if (t + 1 < NT) stage(cur ^ 1, (t + 1) << 6);
        const unsigned short* As = lds + cur * (ASZ + BSZ);
        const unsigned short* Bs = As + ASZ;
#pragma unroll
        for (int kk = 0; kk < 2; ++kk) {
            bf16x8 bq[4];
#pragma unroll
            for (int nt = 0; nt < 4; ++nt) {
                const int r = wn * 64 + nt * 16 + fr;
                bq[nt] = *(const bf16x8*)(Bs + r * 64 + (((kk * 4 + kg) ^ (r & 7)) * 8));
            }
#pragma unroll
            for (int mt = 0; mt < MFM; ++mt) {
                const int r = wm * (MFM * 16) + mt * 16 + fr;
                bf16x8 aq = *(const bf16x8*)(As + r * 64 + (((kk * 4 + kg) ^ (r & 7)) * 8));
#pragma unroll
                for (int nt = 0; nt < 4; ++nt)
                    acc[mt][nt] = __builtin_amdgcn_mfma_f32_16x16x32_bf16(aq, bq[nt], acc[mt][nt], 0, 0, 0);
            }
        }
        __syncthreads();  // drains the prefetch vmcnt + protects buffer swap
        cur ^= 1;
    }

    const int rr = kg * 4;
#pragma unroll
    for (int mt = 0; mt < MFM; ++mt) {
#pragma unroll
        for (int nt = 0; nt < 4; ++nt) {
            const int col = n0 + wn * 64 + nt * 16 + fr;
#pragma unroll
            for (int r = 0; r < 4; ++r) {
                const int row = m0 + wm * (MFM * 16) + mt * 16 + rr + r;
                const float v = acc[mt][nt][r];
                if (MODE == 0) {
                    ((unsigned short*)Out)[(size_t)row * N + col] = f2bf(v);
                } else if (MODE == 1) {
                    ((float*)Out)[(size_t)row * N + col] =
                        v + bias[col] + res[(size_t)row * N + col];
                } else {
                    const float tt = v + bias[col];
                    const float ge = 0.5f * tt * (1.0f + erff(tt * 0.70710678118654752f));
                    ((unsigned short*)Out)[(size_t)row * N + col] = f2bf(ge);
                }
            }
        }
    }
}

// ---------------- Flash attention v2 (unchanged from round 2) ----------------
__global__ __launch_bounds__(256) void attn_kernel(const unsigned short* __restrict__ qkv,
                                                   const int* __restrict__ length,
                                                   unsigned short* __restrict__ y) {
    const int id2 = (blockIdx.x & 7) * 256 + (blockIdx.x >> 3);
    const int qt = id2 & 15;
    const int h = (id2 >> 4) & 15;
    const int b = id2 >> 8;
    const int tid = threadIdx.x, lane = tid & 63, w = tid >> 6;
    const int q0 = qt * 64;
    const int len = length[b];
    const int ntiles = (len + 63) >> 6;

    __shared__ unsigned short Ks[64 * 64];
    __shared__ unsigned short Vs[64 * 64];
    __shared__ unsigned short Ps[4 * 16 * 64];

    const int fr = lane & 15, kg = lane >> 4;

    bf16x8 qf[2];
    {
        const unsigned short* qb = qkv + (size_t)(b * Nn + q0 + w * 16 + fr) * 3072 + h * 64 + kg * 8;
        qf[0] = *(const bf16x8*)(qb);
        qf[1] = *(const bf16x8*)(qb + 32);
    }

    float m[4] = {-1e30f, -1e30f, -1e30f, -1e30f};
    float lsum[4] = {0.f, 0.f, 0.f, 0.f};
    f32x4 accO[4] = {};

    const int krow_l = lane >> 3;
    const int kslot = lane & 7;
    const int vk0 = (tid >> 3) * 2;
    const int vd0 = (tid & 7) * 8;
    const unsigned short* vbase = qkv + (size_t)(b * Nn) * 3072 + 2048 + h * 64 + vd0;

    for (int t = 0; t < ntiles; ++t) {
        const int kv0 = t << 6;
#pragma unroll
        for (int c = 0; c < 2; ++c) {
            const int k = c * 32 + w * 8 + krow_l;
            const int ss = kslot ^ ((k ^ (k >> 3)) & 7);
            gload_lds16(qkv + (size_t)(b * Nn + kv0 + k) * 3072 + 1024 + h * 64 + ss * 8,
                        &Ks[(c * 32 + w * 8) * 64]);
        }
        {
            uint4 v0 = *(const uint4*)(vbase + (size_t)(kv0 + vk0) * 3072);
            uint4 v1 = *(const uint4*)(vbase + (size_t)(kv0 + vk0 + 1) * 3072);
            const unsigned* a0 = (const unsigned*)&v0;
            const unsigned* a1 = (const unsigned*)&v1;
#pragma unroll
            for (int i = 0; i < 8; ++i) {
                const unsigned lo = (a0[i >> 1] >> ((i & 1) * 16)) & 0xffffu;
                const unsigned hi = (a1[i >> 1] >> ((i & 1) * 16)) & 0xffffu;
                const int d = vd0 + i;
                const int off = (d * 128 + vk0 * 2) ^ (((d ^ (d >> 3)) & 7) << 4);
                *(unsigned*)((char*)Vs + off) = lo | (hi << 16);
            }
        }
        __syncthreads();

        f32x4 accS[4] = {};
#pragma unroll
        for (int nt = 0; nt < 4; ++nt) {
            const int kr = nt * 16 + fr;
            const int swz = ((kr ^ (kr >> 3)) & 7) << 4;
#pragma unroll
            for (int kt = 0; kt < 2; ++kt) {
                bf16x8 kf = *(const bf16x8*)((const char*)Ks + ((kr * 128 + (kt * 32 + kg * 8) * 2) ^ swz));
                accS[nt] = __builtin_amdgcn_mfma_f32_16x16x32_bf16(qf[kt], kf, accS[nt], 0, 0, 0);
            }
        }

        float p[4][4], sc[4];
#pragma unroll
        for (int r = 0; r < 4; ++r) {
            float sv[4];
            float mx = -1e30f;
#pragma unroll
            for (int nt = 0; nt < 4; ++nt) {
                sv[nt] = accS[nt][r] * SCALEf + ((kv0 + nt * 16 + fr >= len) ? -10000.0f : 0.0f);
                mx = fmaxf(mx, sv[nt]);
            }
#pragma unroll
            for (int d = 1; d < 16; d <<= 1) mx = fmaxf(mx, __shfl_xor(mx, d, 64));
            const float mnew = fmaxf(m[r], mx);
            sc[r] = __expf(m[r] - mnew);
            float rsum = 0.f;
#pragma unroll
            for (int nt = 0; nt < 4; ++nt) {
                p[nt][r] = __expf(sv[nt] - mnew);
                rsum += p[nt][r];
            }
#pragma unroll
            for (int d = 1; d < 16; d <<= 1) rsum += __shfl_xor(rsum, d, 64);
            lsum[r] = lsum[r] * sc[r] + rsum;
            m[r] = mnew;
        }
#pragma unroll
        for (int nd = 0; nd < 4; ++nd)
#pragma unroll
            for (int r = 0; r < 4; ++r) accO[nd][r] *= sc[r];

#pragma unroll
        for (int r = 0; r < 4; ++r) {
            const int q = kg * 4 + r;
            const int swz = ((q ^ (q >> 3)) & 7) << 4;
#pragma unroll
            for (int nt = 0; nt < 4; ++nt) {
                const int kk = nt * 16 + fr;
                *(unsigned short*)((char*)Ps + ((w * 2048 + q * 128 + kk * 2) ^ swz)) = f2bf(p[nt][r]);
            }
        }
        __builtin_amdgcn_wave_barrier();

        const int swzp = ((fr ^ (fr >> 3)) & 7) << 4;
#pragma unroll
        for (int kt = 0; kt < 2; ++kt) {
            bf16x8 pf = *(const bf16x8*)((const char*)Ps +
                        ((w * 2048 + fr * 128 + (kt * 32 + kg * 8) * 2) ^ swzp));
#pragma unroll
            for (int nd = 0; nd < 4; ++nd) {
                const int d = nd * 16 + fr;
                const int swzv = ((d ^ (d >> 3)) & 7) << 4;
                bf16x8 vf = *(const bf16x8*)((const char*)Vs +
                            ((d * 128 + (kt * 32 + kg * 8) * 2) ^ swzv));
                accO[nd] = __builtin_amdgcn_mfma_f32_16x16x32_bf16(pf, vf, accO[nd], 0, 0, 0);
            }
        }
        __syncthreads();
    }

#pragma unroll
    for (int r = 0; r < 4; ++r) {
        const float inv = 1.0f / lsum[r];
        const int row = q0 + w * 16 + kg * 4 + r;
#pragma unroll
        for (int nd = 0; nd < 4; ++nd)
            y[(size_t)(b * Nn + row) * 1024 + h * 64 + nd * 16 + fr] = f2bf(accO[nd][r] * inv);
    }
}

// ---------------- launch ----------------
extern "C" void kernel_launch(void* const* d_in, const int* in_sizes, int n_in,
                              void* d_out, int out_size, void* d_ws, size_t ws_size,
                              hipStream_t stream) {
    (void)in_sizes; (void)n_in; (void)out_size; (void)ws_size;
    const float* x     = (const float*)d_in[0];
    const int*   len   = (const int*)d_in[1];
    const float* g1    = (const float*)d_in[2];
    const float* b1    = (const float*)d_in[3];
    const float* Wqkv  = (const float*)d_in[4];
    const float* Wproj = (const float*)d_in[5];
    const float* bproj = (const float*)d_in[6];
    const float* g2    = (const float*)d_in[7];
    const float* b2    = (const float*)d_in[8];
    const float* W1    = (const float*)d_in[9];
    const float* bb1   = (const float*)d_in[10];
    const float* W2    = (const float*)d_in[11];
    const float* bb2   = (const float*)d_in[12];
    float* out = (float*)d_out;

    char* ws = (char*)d_ws;
    size_t off = 0;
    auto alloc = [&](size_t bytes) {
        void* p = ws + off;
        off += (bytes + 255) & ~(size_t)255;
        return p;
    };
    unsigned short* xn  = (unsigned short*)alloc(8192ULL * 1024 * 2);
    unsigned short* qkv = (unsigned short*)alloc(8192ULL * 3072 * 2);
    unsigned short* yb  = (unsigned short*)alloc(8192ULL * 1024 * 2);
    float* x2           = (float*)alloc(8192ULL * 1024 * 4);
    unsigned short* wqkv_b  = (unsigned short*)alloc(3072ULL * 1024 * 2);
    unsigned short* wproj_b = (unsigned short*)alloc(1024ULL * 1024 * 2);
    unsigned short* w1_b    = (unsigned short*)alloc(4096ULL * 1024 * 2);
    unsigned short* w2_b    = (unsigned short*)alloc(1024ULL * 4096 * 2);
    unsigned short* hb = qkv;  // reuse: qkv+yb dead by MLP1

    cvt_bf16<<<3072 * 1024 / 4 / 256, 256, 0, stream>>>(Wqkv, wqkv_b, 3072 * 1024 / 4);
    cvt_bf16<<<1024 * 1024 / 4 / 256, 256, 0, stream>>>(Wproj, wproj_b, 1024 * 1024 / 4);
    cvt_bf16<<<4096 * 1024 / 4 / 256, 256, 0, stream>>>(W1, w1_b, 4096 * 1024 / 4);
    cvt_bf16<<<4096 * 1024 / 4 / 256, 256, 0, stream>>>(W2, w2_b, 4096 * 1024 / 4);

    ln_kernel<<<8192, 256, 0, stream>>>(x, g1, b1, xn);
    // QKV: M=8192 N=3072 K=1024, BN=128 -> grid 32*24=768
    gemm2<0, 128><<<768, 512, 0, stream>>>(xn, wqkv_b, qkv, nullptr, nullptr, 8192, 3072, 1024, 24);
    attn_kernel<<<2048, 256, 0, stream>>>(qkv, len, yb);
    // proj: N=1024, BN=128 -> grid 32*8=256
    gemm2<1, 128><<<256, 512, 0, stream>>>(yb, wproj_b, x2, bproj, x, 8192, 1024, 1024, 8);
    ln_kernel<<<8192, 256, 0, stream>>>(x2, g2, b2, xn);
    // MLP1: N=4096, BN=256 -> grid 32*16=512
    gemm2<2, 256><<<512, 512, 0, stream>>>(xn, w1_b, hb, bb1, nullptr, 8192, 4096, 1024, 16);
    // MLP2: N=1024 K=4096, BN=128 -> grid 256
    gemm2<1, 128><<<256, 512, 0, stream>>>(hb, w2_b, out, bb2, x2, 8192, 1024, 4096, 8);
}